// Round 2
// baseline (318.333 us; speedup 1.0000x reference)
//
#include <hip/hip_runtime.h>
#include <hip/hip_bf16.h>

typedef short s16x8 __attribute__((ext_vector_type(8)));
typedef float f32x4 __attribute__((ext_vector_type(4)));
typedef float f32x16 __attribute__((ext_vector_type(16)));

// ---------- helpers ----------
__device__ __forceinline__ unsigned short f2bf(float f) {
  unsigned u = __float_as_uint(f);
  u += 0x7fffu + ((u >> 16) & 1u);   // round-to-nearest-even
  return (unsigned short)(u >> 16);
}

__device__ __forceinline__ void gload16(const void* g, void* l) {
  __builtin_amdgcn_global_load_lds(
      (const __attribute__((address_space(1))) unsigned int*)g,
      (__attribute__((address_space(3))) unsigned int*)l,
      16, 0, 0);
}

// ---------- kernel 1: blockwise FWHT of W rows, scale 1/32, cast bf16 ----------
__global__ void __launch_bounds__(256) k_had_w(const float* __restrict__ W,
                                               unsigned short* __restrict__ Wh) {
  __shared__ float s[1024];
  const size_t base = (size_t)blockIdx.x * 1024;
  const int t = threadIdx.x;

  float4 v = reinterpret_cast<const float4*>(W + base)[t];
  s[4 * t + 0] = v.x;
  s[4 * t + 1] = v.y;
  s[4 * t + 2] = v.z;
  s[4 * t + 3] = v.w;

#pragma unroll
  for (int h = 1; h < 1024; h <<= 1) {
    __syncthreads();
#pragma unroll
    for (int pp = 0; pp < 2; ++pp) {
      int p = t + pp * 256;
      int i = ((p / h) * (h << 1)) + (p % h);
      float a = s[i], b = s[i + h];
      s[i] = a + b;
      s[i + h] = a - b;
    }
  }
  __syncthreads();

  const float sc = 0.03125f;  // 1/sqrt(1024)
  ushort4 o;
  o.x = f2bf(s[4 * t + 0] * sc);
  o.y = f2bf(s[4 * t + 1] * sc);
  o.z = f2bf(s[4 * t + 2] * sc);
  o.w = f2bf(s[4 * t + 3] * sc);
  reinterpret_cast<ushort4*>(Wh + base)[t] = o;
}

// ---------- kernel 2: x f32 -> bf16 ----------
__global__ void __launch_bounds__(256) k_cast(const float* __restrict__ x,
                                              unsigned short* __restrict__ xb,
                                              long n4) {
  long i = (long)blockIdx.x * 256 + threadIdx.x;
  const long stride = (long)gridDim.x * 256;
  for (; i < n4; i += stride) {
    float4 v = reinterpret_cast<const float4*>(x)[i];
    ushort4 o;
    o.x = f2bf(v.x);
    o.y = f2bf(v.y);
    o.z = f2bf(v.z);
    o.w = f2bf(v.w);
    reinterpret_cast<ushort4*>(xb)[i] = o;
  }
}

// ---------- kernel 3: 256x256 bf16 GEMM, R4 schedule, 32x32x16 MFMA ----------
// A: [M][K] bf16, B: [N][K] bf16, C: [M][N] f32.
// 8 waves (2M x 4N), BK=64. LDS: A 3x32KB (triple buffer) + B 2x32KB = 160KB.
// Swizzle v2: chunk involution swz(row) = (row&7) ^ (((row>>3)&3)<<1).
//   Old (row&7)-only swizzle left lanes {l,l+8,l+16,l+24} on one bank-quad
//   (4-way, 2.5e7 conflicts/dispatch). Adding row bits[4:3] into chunk bits[2:1]
//   spreads every stride-8 lane group across 8 distinct quads; consecutive-8
//   groups stay fully distinct; all groupings >= the proven-0-conflict pattern.
// A/B operand: lane l holds row/col (l&31), k = 8*(l>>5)+e  (one 16B chunk).
// C/D layout (32x32): col = lane&31, row = (reg&3)+8*(reg>>2)+4*(lane>>5)  [m74/m101]

#define STAGE_HALF(gbase, halfRow, koff, ldsDst)                             \
  do {                                                                       \
    gload16(gbase + (size_t)(halfRow)*K + (koff), (ldsDst) + tid * 16);      \
    gload16(gbase + (size_t)((halfRow) + 64)*K + (koff),                     \
            (ldsDst) + 8192 + tid * 16);                                     \
  } while (0)

// A fragments for one M-half (msel): 2 frags x 4 k-slices = 8 x ds_read_b128
#define RD_A(bufp, dst, msel)                                                \
  do { _Pragma("unroll")                                                     \
    for (int i = 0; i < 2; ++i) { _Pragma("unroll")                          \
      for (int kk = 0; kk < 4; ++kk) {                                       \
        dst[i][kk] = *(const s16x8*)((bufp) + abase + (msel)*8192 +          \
                                     i * 4096 + cs[kk]);                     \
      } } } while (0)

// B fragment for one N-half (nsel): 1 frag x 4 k-slices = 4 x ds_read_b128
#define RD_B(bufp, dst, nsel)                                                \
  do { _Pragma("unroll")                                                     \
    for (int kk = 0; kk < 4; ++kk) {                                         \
      dst[kk] = *(const s16x8*)((bufp) + bbase + (nsel)*4096 + cs[kk]);      \
    } } while (0)

#define MFMA_Q(msel, nsel, AF, BF)                                           \
  do {                                                                       \
    __builtin_amdgcn_s_setprio(1);                                           \
    _Pragma("unroll")                                                        \
    for (int kk = 0; kk < 4; ++kk) {                                         \
      _Pragma("unroll")                                                      \
      for (int i = 0; i < 2; ++i) {                                          \
        acc[(msel)*2 + i][nsel] =                                            \
          __builtin_amdgcn_mfma_f32_32x32x16_bf16(                           \
            AF[i][kk], BF[kk], acc[(msel)*2 + i][nsel], 0, 0, 0);            \
      }                                                                      \
    }                                                                        \
    __builtin_amdgcn_s_setprio(0);                                           \
  } while (0)

#define BAR() __builtin_amdgcn_s_barrier()

__global__ void __launch_bounds__(512, 2) k_gemm256(
    const unsigned short* __restrict__ A, const unsigned short* __restrict__ B,
    const float* __restrict__ bias, float* __restrict__ C,
    int M, int N, int K) {
  __shared__ char LDS[163840];   // A: 3 x 32KB @ 0/32768/65536; B: 2 x 32KB @ 98304/131072

  const int tid = threadIdx.x;
  const int lane = tid & 63;
  const int wid = tid >> 6;
  const int wm = wid >> 2;     // 0..1
  const int wn = wid & 3;      // 0..3
  const int r31 = lane & 31;   // row/col within 32x32 fragment
  const int h = lane >> 5;     // k-half selector

  // XCD-aware bijective swizzle (grid = 512, divisible by 8)
  const int nbn = N >> 8;
  const int cpx = gridDim.x >> 3;
  const int swz = (blockIdx.x & 7) * cpx + (blockIdx.x >> 3);
  const int bm = swz / nbn, bn = swz % nbn;

  // ---- staging addressing (linear LDS dest, pre-swizzled global source) ----
  // involution: global chunk g of row r lives at LDS slot g ^ swz(r),
  // swz(r) = (r&7) ^ (((r>>3)&3)<<1)   (invariant under row +32/+64/+128)
  const int r0 = tid >> 3;
  const int ck = (tid & 7) ^ (r0 & 7) ^ (((r0 >> 3) & 3) << 1);
  const unsigned short* gAbase = A + (size_t)(bm * 256 + r0) * K + ck * 8;
  const unsigned short* gBbase = B + (size_t)(bn * 256 + r0) * K + ck * 8;

  // ---- fragment read offsets (0-conflict chunk swizzle v2) ----
  // k-slice kk, k-half h -> global chunk (2*kk + h); LDS slot = chunk ^ swz(r31)
  const int rsw = (r31 & 7) ^ (((r31 >> 3) & 3) << 1);
  int cs[4];
#pragma unroll
  for (int kk = 0; kk < 4; ++kk)
    cs[kk] = (((kk * 2 + h) ^ rsw) << 4);
  const int abase = wm * 16384 + r31 * 128;
  const int bbase = (wn >> 1) * 16384 + (wn & 1) * 8192 + r31 * 128;

  f32x16 acc[4][2];
#pragma unroll
  for (int m = 0; m < 4; ++m)
#pragma unroll
    for (int n = 0; n < 2; ++n)
#pragma unroll
      for (int j = 0; j < 16; ++j) acc[m][n][j] = 0.f;

  s16x8 af0[2][4], af1[2][4], bf0[4], bf1[4];

  // ---- prologue: A(0)->bufA0, B(0)->bufB0, A(1)->bufA1, B(1)->bufB1 ----
  STAGE_HALF(gAbase, 0,   0, LDS);                    // A(0) rows 0-127
  STAGE_HALF(gAbase, 128, 0, LDS + 16384);            // A(0) rows 128-255
  STAGE_HALF(gBbase, 0,   0, LDS + 98304);            // B(0) rows 0-127
  STAGE_HALF(gBbase, 128, 0, LDS + 98304 + 16384);    // B(0) rows 128-255
  STAGE_HALF(gAbase, 0,   64, LDS + 32768);           // A(1)
  STAGE_HALF(gAbase, 128, 64, LDS + 32768 + 16384);
  STAGE_HALF(gBbase, 0,   64, LDS + 131072);          // B(1)
  STAGE_HALF(gBbase, 128, 64, LDS + 131072 + 16384);
  asm volatile("s_waitcnt vmcnt(8)" ::: "memory");    // A(0),B(0) landed
  BAR();
  RD_A(LDS, af0, 0);
  RD_B(LDS + 98304, bf0, 0);

  const int nt = K >> 6;  // 64
  int am = 0, an = 1, an2 = 2;   // A buffer rotation (t, t+1, t+2) mod 3
  for (int t = 0; t < nt; ++t) {
    const char* bA  = LDS + am * 32768;
    const char* bAn = LDS + an * 32768;
    char*       bAs = LDS + an2 * 32768;                    // A(t+2) dest
    const char* bB  = LDS + 98304 + ((t & 1) << 15);
    const char* bBn = LDS + 98304 + (((t + 1) & 1) << 15);
    char*       bBs = (char*)bB;                            // B(t+2) dest (same parity)
    const int koff2 = (t + 2) << 6;

    // ---- ph1: reads bf1+af1 (12); stage A(t+2) rows 0-127; BAR; q(0,0)
    RD_B(bB, bf1, 1);
    RD_A(bA, af1, 1);
    if (t + 2 < nt) STAGE_HALF(gAbase, 0, koff2, bAs);
    BAR();
    MFMA_Q(0, 0, af0, bf0);

    // ---- ph2: stage A(t+2) rows 128-255; BAR; q(0,1)
    if (t + 2 < nt) STAGE_HALF(gAbase, 128, koff2, bAs + 16384);
    BAR();
    MFMA_Q(0, 1, af0, bf1);

    // ---- ph3: stage B(t+2) rows 0-127 (bf0/bf1(t) reads drained >=1 BAR ago);
    //      BAR; q(1,0)
    if (t + 2 < nt) STAGE_HALF(gBbase, 0, koff2, bBs);
    BAR();
    MFMA_Q(1, 0, af1, bf0);

    // ---- ph4: stage B(t+2) rows 128-255; counted vmcnt; BAR;
    //      next-tile af0/bf0 reads; q(1,1)
    if (t + 2 < nt) STAGE_HALF(gBbase, 128, koff2, bBs + 16384);
    if (t < nt - 2) {
      asm volatile("s_waitcnt vmcnt(8)" ::: "memory");  // A(t+1),B(t+1) landed
    } else if (t == nt - 2) {
      asm volatile("s_waitcnt vmcnt(0)" ::: "memory");  // tail drain
    }
    BAR();
    if (t + 1 < nt) {
      RD_A(bAn, af0, 0);
      RD_B(bBn, bf0, 0);
    }
    MFMA_Q(1, 1, af1, bf1);

    // rotate A buffers
    const int tmp = am;
    am = an; an = an2; an2 = tmp;
  }

  // ---- epilogue: C = acc + bias ----
  // C/D layout (32x32): col = lane&31, row = (reg&3)+8*(reg>>2)+4*(lane>>5)
  const int row0 = bm * 256 + wm * 128;
  const int col0 = bn * 256 + wn * 64;
  float bv[2];
#pragma unroll
  for (int nf = 0; nf < 2; ++nf) bv[nf] = bias[col0 + nf * 32 + r31];

#pragma unroll
  for (int mf = 0; mf < 4; ++mf) {
#pragma unroll
    for (int nf = 0; nf < 2; ++nf) {
#pragma unroll
      for (int reg = 0; reg < 16; ++reg) {
        const int r = row0 + mf * 32 + (reg & 3) + ((reg >> 2) << 3) + (h << 2);
        const int c = col0 + nf * 32 + r31;
        C[(size_t)r * N + c] = acc[mf][nf][reg] + bv[nf];
      }
    }
  }
}

// ---------- launcher ----------
extern "C" void kernel_launch(void* const* d_in, const int* in_sizes, int n_in,
                              void* d_out, int out_size, void* d_ws, size_t ws_size,
                              hipStream_t stream) {
  const float* x = (const float*)d_in[0];
  const float* W = (const float*)d_in[1];
  const float* b = (const float*)d_in[2];
  float* out = (float*)d_out;

  const int N = in_sizes[2];                 // 4096 (D_OUT)
  const int K = in_sizes[1] / N;             // 4096 (D_IN)
  const int M = in_sizes[0] / K;             // 8192 (B*S)

  unsigned short* Xb = (unsigned short*)d_ws;              // M*K bf16
  unsigned short* Wh = Xb + (size_t)M * K;                 // N*K bf16

  const int nblk = (int)(((size_t)N * K) / 1024);
  k_had_w<<<nblk, 256, 0, stream>>>(W, Wh);

  const long n4 = ((long)M * K) / 4;
  k_cast<<<4096, 256, 0, stream>>>(x, Xb, n4);

  const int grid = (M / 256) * (N / 256);    // 512
  k_gemm256<<<grid, 512, 0, stream>>>(Xb, Wh, b, out, M, N, K);
}

// Round 3
// 301.278 us; speedup vs baseline: 1.0566x; 1.0566x over previous
//
#include <hip/hip_runtime.h>
#include <hip/hip_bf16.h>

typedef short s16x8 __attribute__((ext_vector_type(8)));
typedef float f32x4 __attribute__((ext_vector_type(4)));

// ---------- helpers ----------
__device__ __forceinline__ unsigned short f2bf(float f) {
  unsigned u = __float_as_uint(f);
  u += 0x7fffu + ((u >> 16) & 1u);   // round-to-nearest-even
  return (unsigned short)(u >> 16);
}

__device__ __forceinline__ void gload16(const void* g, void* l) {
  __builtin_amdgcn_global_load_lds(
      (const __attribute__((address_space(1))) unsigned int*)g,
      (__attribute__((address_space(3))) unsigned int*)l,
      16, 0, 0);
}

// ---------- kernel 1: blockwise FWHT of W rows, scale 1/32, cast bf16 ----------
__global__ void __launch_bounds__(256) k_had_w(const float* __restrict__ W,
                                               unsigned short* __restrict__ Wh) {
  __shared__ float s[1024];
  const size_t base = (size_t)blockIdx.x * 1024;
  const int t = threadIdx.x;

  float4 v = reinterpret_cast<const float4*>(W + base)[t];
  s[4 * t + 0] = v.x;
  s[4 * t + 1] = v.y;
  s[4 * t + 2] = v.z;
  s[4 * t + 3] = v.w;

#pragma unroll
  for (int h = 1; h < 1024; h <<= 1) {
    __syncthreads();
#pragma unroll
    for (int pp = 0; pp < 2; ++pp) {
      int p = t + pp * 256;
      int i = ((p / h) * (h << 1)) + (p % h);
      float a = s[i], b = s[i + h];
      s[i] = a + b;
      s[i + h] = a - b;
    }
  }
  __syncthreads();

  const float sc = 0.03125f;  // 1/sqrt(1024)
  ushort4 o;
  o.x = f2bf(s[4 * t + 0] * sc);
  o.y = f2bf(s[4 * t + 1] * sc);
  o.z = f2bf(s[4 * t + 2] * sc);
  o.w = f2bf(s[4 * t + 3] * sc);
  reinterpret_cast<ushort4*>(Wh + base)[t] = o;
}

// ---------- kernel 2: x f32 -> bf16 ----------
__global__ void __launch_bounds__(256) k_cast(const float* __restrict__ x,
                                              unsigned short* __restrict__ xb,
                                              long n4) {
  long i = (long)blockIdx.x * 256 + threadIdx.x;
  const long stride = (long)gridDim.x * 256;
  for (; i < n4; i += stride) {
    float4 v = reinterpret_cast<const float4*>(x)[i];
    ushort4 o;
    o.x = f2bf(v.x);
    o.y = f2bf(v.y);
    o.z = f2bf(v.z);
    o.w = f2bf(v.w);
    reinterpret_cast<ushort4*>(xb)[i] = o;
  }
}

// ---------- kernel 3: 256x256 bf16 GEMM, 16x16x32 MFMA, m201 phase shape ----------
// A: [M][K] bf16, B: [N][K] bf16, C: [M][N] f32.
// 8 waves (2M x 4N), BK=64. LDS: A 3x32KB (triple buffer) + B 2x32KB = 160KB.
// Proven 16x16 fragment/swizzle addressing (0 bank conflicts measured).
// Phase shape per m201: each phase = {ds-reads (4-8) | 2 gloads | [vmcnt] | BAR |
//   setprio(1) 16xMFMA setprio(0) | BAR}.  Counted vmcnt(10)/(8) in ph3/ph4,
// next-tile fragment reads placed AFTER the barrier (barrier publishes all
// waves' DMA; vmcnt alone is per-wave).

#define STAGE_HALF(gbase, halfRow, koff, ldsDst)                             \
  do {                                                                       \
    gload16(gbase + (size_t)(halfRow)*K + (koff), (ldsDst) + tid * 16);      \
    gload16(gbase + (size_t)((halfRow) + 64)*K + (koff),                     \
            (ldsDst) + 8192 + tid * 16);                                     \
  } while (0)

#define RD_AF0(bufp)                                                         \
  do { _Pragma("unroll")                                                     \
    for (int i = 0; i < 4; ++i) {                                            \
      af0[i][0] = *(const s16x8*)((bufp) + aoff0 + i * 2048);                \
      af0[i][1] = *(const s16x8*)((bufp) + aoff1 + i * 2048);                \
    } } while (0)

#define RD_AF1(bufp)                                                         \
  do { _Pragma("unroll")                                                     \
    for (int i = 0; i < 4; ++i) {                                            \
      af1[i][0] = *(const s16x8*)((bufp) + aoff0 + 8192 + i * 2048);         \
      af1[i][1] = *(const s16x8*)((bufp) + aoff1 + 8192 + i * 2048);         \
    } } while (0)

#define RD_BF0(bufp)                                                         \
  do { _Pragma("unroll")                                                     \
    for (int j2 = 0; j2 < 2; ++j2) {                                         \
      bf0[j2][0] = *(const s16x8*)((bufp) + boff0 + j2 * 2048);              \
      bf0[j2][1] = *(const s16x8*)((bufp) + boff1 + j2 * 2048);              \
    } } while (0)

#define RD_BF1(bufp)                                                         \
  do { _Pragma("unroll")                                                     \
    for (int j2 = 0; j2 < 2; ++j2) {                                         \
      bf1[j2][0] = *(const s16x8*)((bufp) + boff0 + 4096 + j2 * 2048);       \
      bf1[j2][1] = *(const s16x8*)((bufp) + boff1 + 4096 + j2 * 2048);       \
    } } while (0)

#define MFMA_Q(msel, nsel, AF, BF)                                           \
  do {                                                                       \
    __builtin_amdgcn_s_setprio(1);                                           \
    _Pragma("unroll")                                                        \
    for (int kk = 0; kk < 2; ++kk) {                                         \
      _Pragma("unroll")                                                      \
      for (int i = 0; i < 4; ++i) {                                          \
        _Pragma("unroll")                                                    \
        for (int j2 = 0; j2 < 2; ++j2) {                                     \
          acc[(msel)*4 + i][(nsel)*2 + j2] =                                 \
            __builtin_amdgcn_mfma_f32_16x16x32_bf16(                         \
              AF[i][kk], BF[j2][kk], acc[(msel)*4 + i][(nsel)*2 + j2],       \
              0, 0, 0);                                                      \
        }                                                                    \
      }                                                                      \
    }                                                                        \
    __builtin_amdgcn_s_setprio(0);                                           \
  } while (0)

#define BAR() __builtin_amdgcn_s_barrier()

__global__ void __launch_bounds__(512, 2) k_gemm256(
    const unsigned short* __restrict__ A, const unsigned short* __restrict__ B,
    const float* __restrict__ bias, float* __restrict__ C,
    int M, int N, int K) {
  __shared__ char LDS[163840];   // A: 3 x 32KB @ 0/32768/65536; B: 2 x 32KB @ 98304/131072

  const int tid = threadIdx.x;
  const int lane = tid & 63;
  const int wid = tid >> 6;
  const int wm = wid >> 2;     // 0..1
  const int wn = wid & 3;      // 0..3
  const int fr = lane & 15;
  const int fq = lane >> 4;

  // XCD-aware bijective swizzle (grid = 512, divisible by 8)
  const int nbn = N >> 8;
  const int cpx = gridDim.x >> 3;
  const int swz = (blockIdx.x & 7) * cpx + (blockIdx.x >> 3);
  const int bm = swz / nbn, bn = swz % nbn;

  // ---- staging addressing (linear LDS dest, pre-swizzled global source) ----
  const int r0 = tid >> 3;
  const int ck = (tid & 7) ^ (r0 & 7);
  const unsigned short* gAbase = A + (size_t)(bm * 256 + r0) * K + ck * 8;
  const unsigned short* gBbase = B + (size_t)(bn * 256 + r0) * K + ck * 8;

  // ---- fragment read offsets, local to a 32KB tile (0-conflict pattern) ----
  const int cs0 = ((fq ^ (fr & 7)) << 4);        // kk=0 chunk byte offset
  const int cs1 = (((fq + 4) ^ (fr & 7)) << 4);  // kk=1
  const int aoff0 = wm * 16384 + fr * 128 + cs0;
  const int aoff1 = wm * 16384 + fr * 128 + cs1;
  const int bbase0 = (wn >> 1) * 16384 + (wn & 1) * 8192 + fr * 128;
  const int boff0 = bbase0 + cs0;
  const int boff1 = bbase0 + cs1;

  f32x4 acc[8][4];
#pragma unroll
  for (int m = 0; m < 8; ++m)
#pragma unroll
    for (int n = 0; n < 4; ++n)
      acc[m][n] = (f32x4){0.f, 0.f, 0.f, 0.f};

  s16x8 af0[4][2], af1[4][2], bf0[2][2], bf1[2][2];

  // ---- prologue: A(0)->bufA0, B(0)->bufB0, A(1)->bufA1, B(1)->bufB1 ----
  STAGE_HALF(gAbase, 0,   0, LDS);                    // A(0) rows 0-127
  STAGE_HALF(gAbase, 128, 0, LDS + 16384);            // A(0) rows 128-255
  STAGE_HALF(gBbase, 0,   0, LDS + 98304);            // B(0) rows 0-127
  STAGE_HALF(gBbase, 128, 0, LDS + 98304 + 16384);    // B(0) rows 128-255
  STAGE_HALF(gAbase, 0,   64, LDS + 32768);           // A(1)
  STAGE_HALF(gAbase, 128, 64, LDS + 32768 + 16384);
  STAGE_HALF(gBbase, 0,   64, LDS + 131072);          // B(1)
  STAGE_HALF(gBbase, 128, 64, LDS + 131072 + 16384);
  asm volatile("s_waitcnt vmcnt(8)" ::: "memory");    // A(0),B(0) landed
  BAR();
  RD_AF0(LDS);
  RD_BF0(LDS + 98304);

  const int nt = K >> 6;  // 64
  int am = 0, an = 1, an2 = 2;   // A buffer rotation (t, t+1, t+2) mod 3
  for (int t = 0; t < nt; ++t) {
    const char* bA  = LDS + am * 32768;
    const char* bAn = LDS + an * 32768;
    char*       bAs = LDS + an2 * 32768;                    // A(t+2) dest
    const char* bB  = LDS + 98304 + ((t & 1) << 15);
    const char* bBn = LDS + 98304 + (((t + 1) & 1) << 15);
    char*       bBs = (char*)bB;                            // B(t+2) dest (same parity)
    const int koff2 = (t + 2) << 6;

    // ---- ph1: read bf1(t) [4]; stage A(t+2) h0; BAR; q(0,0); BAR
    RD_BF1(bB);
    if (t + 2 < nt) STAGE_HALF(gAbase, 0, koff2, bAs);
    BAR();
    MFMA_Q(0, 0, af0, bf0);
    BAR();

    // ---- ph2: read af1(t) [8]; stage A(t+2) h1; BAR; q(0,1); BAR
    RD_AF1(bA);
    if (t + 2 < nt) STAGE_HALF(gAbase, 128, koff2, bAs + 16384);
    BAR();
    MFMA_Q(0, 1, af0, bf1);
    BAR();

    // ---- ph3: stage B(t+2) h0; counted vmcnt (A(t+1) landed); BAR;
    //      read af0(t+1) [8]; q(1,0); BAR
    if (t + 2 < nt) STAGE_HALF(gBbase, 0, koff2, bBs);
    if (t + 1 < nt) {
      if (t + 2 < nt) {
        asm volatile("s_waitcnt vmcnt(10)" ::: "memory");  // retire A(t+1)
      } else {
        asm volatile("s_waitcnt vmcnt(4)" ::: "memory");   // tail: retire A(nt-1)
      }
    }
    BAR();
    if (t + 1 < nt) RD_AF0(bAn);
    MFMA_Q(1, 0, af1, bf0);
    BAR();

    // ---- ph4: stage B(t+2) h1; counted vmcnt (B(t+1) landed); BAR;
    //      read bf0(t+1) [4]; q(1,1); BAR
    if (t + 2 < nt) STAGE_HALF(gBbase, 128, koff2, bBs + 16384);
    if (t + 1 < nt) {
      if (t + 2 < nt) {
        asm volatile("s_waitcnt vmcnt(8)" ::: "memory");   // retire B(t+1)
      } else {
        asm volatile("s_waitcnt vmcnt(0)" ::: "memory");   // tail drain
      }
    }
    BAR();
    if (t + 1 < nt) RD_BF0(bBn);
    MFMA_Q(1, 1, af1, bf1);
    BAR();

    // rotate A buffers
    const int tmp = am;
    am = an; an = an2; an2 = tmp;
  }

  // ---- epilogue: C = acc + bias ----
  // C/D layout (16x16): col = lane&15, row = (lane>>4)*4 + reg  [m89/m91]
  const int row0 = bm * 256 + wm * 128;
  const int col0 = bn * 256 + wn * 64;
  float bv[4];
#pragma unroll
  for (int nf = 0; nf < 4; ++nf) bv[nf] = bias[col0 + nf * 16 + fr];

#pragma unroll
  for (int mf = 0; mf < 8; ++mf) {
#pragma unroll
    for (int nf = 0; nf < 4; ++nf) {
#pragma unroll
      for (int i = 0; i < 4; ++i) {
        const int r = row0 + mf * 16 + fq * 4 + i;
        const int c = col0 + nf * 16 + fr;
        C[(size_t)r * N + c] = acc[mf][nf][i] + bv[nf];
      }
    }
  }
}

// ---------- launcher ----------
extern "C" void kernel_launch(void* const* d_in, const int* in_sizes, int n_in,
                              void* d_out, int out_size, void* d_ws, size_t ws_size,
                              hipStream_t stream) {
  const float* x = (const float*)d_in[0];
  const float* W = (const float*)d_in[1];
  const float* b = (const float*)d_in[2];
  float* out = (float*)d_out;

  const int N = in_sizes[2];                 // 4096 (D_OUT)
  const int K = in_sizes[1] / N;             // 4096 (D_IN)
  const int M = in_sizes[0] / K;             // 8192 (B*S)

  unsigned short* Xb = (unsigned short*)d_ws;              // M*K bf16
  unsigned short* Wh = Xb + (size_t)M * K;                 // N*K bf16

  const int nblk = (int)(((size_t)N * K) / 1024);
  k_had_w<<<nblk, 256, 0, stream>>>(W, Wh);

  const long n4 = ((long)M * K) / 4;
  k_cast<<<4096, 256, 0, stream>>>(x, Xb, n4);

  const int grid = (M / 256) * (N / 256);    // 512
  k_gemm256<<<grid, 512, 0, stream>>>(Xb, Wh, b, out, M, N, K);
}

// Round 4
// 288.116 us; speedup vs baseline: 1.1049x; 1.0457x over previous
//
#include <hip/hip_runtime.h>
#include <hip/hip_bf16.h>

typedef short s16x8 __attribute__((ext_vector_type(8)));
typedef float f32x4 __attribute__((ext_vector_type(4)));

// ---------- helpers ----------
__device__ __forceinline__ unsigned short f2bf(float f) {
  unsigned u = __float_as_uint(f);
  u += 0x7fffu + ((u >> 16) & 1u);   // round-to-nearest-even
  return (unsigned short)(u >> 16);
}

__device__ __forceinline__ void gload16(const void* g, void* l) {
  __builtin_amdgcn_global_load_lds(
      (const __attribute__((address_space(1))) unsigned int*)g,
      (__attribute__((address_space(3))) unsigned int*)l,
      16, 0, 0);
}

// ---------- kernel 1: blockwise FWHT of W rows, scale 1/32, cast bf16 ----------
__global__ void __launch_bounds__(256) k_had_w(const float* __restrict__ W,
                                               unsigned short* __restrict__ Wh) {
  __shared__ float s[1024];
  const size_t base = (size_t)blockIdx.x * 1024;
  const int t = threadIdx.x;

  float4 v = reinterpret_cast<const float4*>(W + base)[t];
  s[4 * t + 0] = v.x;
  s[4 * t + 1] = v.y;
  s[4 * t + 2] = v.z;
  s[4 * t + 3] = v.w;

#pragma unroll
  for (int h = 1; h < 1024; h <<= 1) {
    __syncthreads();
#pragma unroll
    for (int pp = 0; pp < 2; ++pp) {
      int p = t + pp * 256;
      int i = ((p / h) * (h << 1)) + (p % h);
      float a = s[i], b = s[i + h];
      s[i] = a + b;
      s[i + h] = a - b;
    }
  }
  __syncthreads();

  const float sc = 0.03125f;  // 1/sqrt(1024)
  ushort4 o;
  o.x = f2bf(s[4 * t + 0] * sc);
  o.y = f2bf(s[4 * t + 1] * sc);
  o.z = f2bf(s[4 * t + 2] * sc);
  o.w = f2bf(s[4 * t + 3] * sc);
  reinterpret_cast<ushort4*>(Wh + base)[t] = o;
}

// ---------- kernel 2: x f32 -> bf16 ----------
__global__ void __launch_bounds__(256) k_cast(const float* __restrict__ x,
                                              unsigned short* __restrict__ xb,
                                              long n4) {
  long i = (long)blockIdx.x * 256 + threadIdx.x;
  const long stride = (long)gridDim.x * 256;
  for (; i < n4; i += stride) {
    float4 v = reinterpret_cast<const float4*>(x)[i];
    ushort4 o;
    o.x = f2bf(v.x);
    o.y = f2bf(v.y);
    o.z = f2bf(v.z);
    o.w = f2bf(v.w);
    reinterpret_cast<ushort4*>(xb)[i] = o;
  }
}

// ---------- kernel 3: 256x256 bf16 GEMM, R4 schedule + fine read interleave ----
// A: [M][K] bf16, B: [N][K] bf16, C: [M][N] f32.
// 8 waves (2M x 4N), BK=64. LDS: A 3x32KB (triple buffer) + B 2x32KB = 160KB.
// Identical sync skeleton to the 237.6us baseline (4 barriers/tile, A(t+2)
// staged ph1/ph2, B(t+2) ph3/ph4). Change: fragment reads spread 4/8/8/4
// across phases (was 12/0/0/12) per m196's fine-interleave finding.
//   ph1: rd bf1(t)      ph2: rd af1(t), vmcnt(8) retires A(t+1)
//   ph3: rd af0(t+1)    ph4: vmcnt(8) retires B(t+1); rd bf0(t+1) post-BAR
// Ledger: after ph2 staging, outstanding <= {A(t+1)?,B(t+1),A(t+2)}=12;
// vmcnt(8) forces A(t+1) landed; ph2 BAR publishes -> ph3 af0(t+1) reads safe.
// Tail t=nt-2: no A(t+2) staged -> ph2 uses vmcnt(4); ph4 vmcnt(0) as before.

#define STAGE_HALF(gbase, halfRow, koff, ldsDst)                             \
  do {                                                                       \
    gload16(gbase + (size_t)(halfRow)*K + (koff), (ldsDst) + tid * 16);      \
    gload16(gbase + (size_t)((halfRow) + 64)*K + (koff),                     \
            (ldsDst) + 8192 + tid * 16);                                     \
  } while (0)

#define RD_AF0(bufp)                                                         \
  do { _Pragma("unroll")                                                     \
    for (int i = 0; i < 4; ++i) {                                            \
      af0[i][0] = *(const s16x8*)((bufp) + aoff0 + i * 2048);                \
      af0[i][1] = *(const s16x8*)((bufp) + aoff1 + i * 2048);                \
    } } while (0)

#define RD_AF1(bufp)                                                         \
  do { _Pragma("unroll")                                                     \
    for (int i = 0; i < 4; ++i) {                                            \
      af1[i][0] = *(const s16x8*)((bufp) + aoff0 + 8192 + i * 2048);         \
      af1[i][1] = *(const s16x8*)((bufp) + aoff1 + 8192 + i * 2048);         \
    } } while (0)

#define RD_BF0(bufp)                                                         \
  do { _Pragma("unroll")                                                     \
    for (int j2 = 0; j2 < 2; ++j2) {                                         \
      bf0[j2][0] = *(const s16x8*)((bufp) + boff0 + j2 * 2048);              \
      bf0[j2][1] = *(const s16x8*)((bufp) + boff1 + j2 * 2048);              \
    } } while (0)

#define RD_BF1(bufp)                                                         \
  do { _Pragma("unroll")                                                     \
    for (int j2 = 0; j2 < 2; ++j2) {                                         \
      bf1[j2][0] = *(const s16x8*)((bufp) + boff0 + 4096 + j2 * 2048);       \
      bf1[j2][1] = *(const s16x8*)((bufp) + boff1 + 4096 + j2 * 2048);       \
    } } while (0)

#define MFMA_Q(msel, nsel, AF, BF)                                           \
  do {                                                                       \
    __builtin_amdgcn_s_setprio(1);                                           \
    _Pragma("unroll")                                                        \
    for (int kk = 0; kk < 2; ++kk) {                                         \
      _Pragma("unroll")                                                      \
      for (int i = 0; i < 4; ++i) {                                          \
        _Pragma("unroll")                                                    \
        for (int j2 = 0; j2 < 2; ++j2) {                                     \
          acc[(msel)*4 + i][(nsel)*2 + j2] =                                 \
            __builtin_amdgcn_mfma_f32_16x16x32_bf16(                         \
              AF[i][kk], BF[j2][kk], acc[(msel)*4 + i][(nsel)*2 + j2],       \
              0, 0, 0);                                                      \
        }                                                                    \
      }                                                                      \
    }                                                                        \
    __builtin_amdgcn_s_setprio(0);                                           \
  } while (0)

#define BAR() __builtin_amdgcn_s_barrier()

__global__ void __launch_bounds__(512, 2) k_gemm256(
    const unsigned short* __restrict__ A, const unsigned short* __restrict__ B,
    const float* __restrict__ bias, float* __restrict__ C,
    int M, int N, int K) {
  __shared__ char LDS[163840];   // A: 3 x 32KB @ 0/32768/65536; B: 2 x 32KB @ 98304/131072

  const int tid = threadIdx.x;
  const int lane = tid & 63;
  const int wid = tid >> 6;
  const int wm = wid >> 2;     // 0..1
  const int wn = wid & 3;      // 0..3
  const int fr = lane & 15;
  const int fq = lane >> 4;

  // XCD-aware bijective swizzle (grid = 512, divisible by 8)
  const int nbn = N >> 8;
  const int cpx = gridDim.x >> 3;
  const int swz = (blockIdx.x & 7) * cpx + (blockIdx.x >> 3);
  const int bm = swz / nbn, bn = swz % nbn;

  // ---- staging addressing (linear LDS dest, pre-swizzled global source) ----
  const int r0 = tid >> 3;
  const int ck = (tid & 7) ^ (r0 & 7);
  const unsigned short* gAbase = A + (size_t)(bm * 256 + r0) * K + ck * 8;
  const unsigned short* gBbase = B + (size_t)(bn * 256 + r0) * K + ck * 8;

  // ---- fragment read offsets, local to a 32KB tile (0-conflict pattern) ----
  const int cs0 = ((fq ^ (fr & 7)) << 4);        // kk=0 chunk byte offset
  const int cs1 = (((fq + 4) ^ (fr & 7)) << 4);  // kk=1
  const int aoff0 = wm * 16384 + fr * 128 + cs0;
  const int aoff1 = wm * 16384 + fr * 128 + cs1;
  const int bbase0 = (wn >> 1) * 16384 + (wn & 1) * 8192 + fr * 128;
  const int boff0 = bbase0 + cs0;
  const int boff1 = bbase0 + cs1;

  f32x4 acc[8][4];
#pragma unroll
  for (int m = 0; m < 8; ++m)
#pragma unroll
    for (int n = 0; n < 4; ++n)
      acc[m][n] = (f32x4){0.f, 0.f, 0.f, 0.f};

  s16x8 af0[4][2], af1[4][2], bf0[2][2], bf1[2][2];

  // ---- prologue: A(0)->bufA0, B(0)->bufB0, A(1)->bufA1, B(1)->bufB1 ----
  STAGE_HALF(gAbase, 0,   0, LDS);                    // A(0) rows 0-127
  STAGE_HALF(gAbase, 128, 0, LDS + 16384);            // A(0) rows 128-255
  STAGE_HALF(gBbase, 0,   0, LDS + 98304);            // B(0) rows 0-127
  STAGE_HALF(gBbase, 128, 0, LDS + 98304 + 16384);    // B(0) rows 128-255
  STAGE_HALF(gAbase, 0,   64, LDS + 32768);           // A(1)
  STAGE_HALF(gAbase, 128, 64, LDS + 32768 + 16384);
  STAGE_HALF(gBbase, 0,   64, LDS + 131072);          // B(1)
  STAGE_HALF(gBbase, 128, 64, LDS + 131072 + 16384);
  asm volatile("s_waitcnt vmcnt(8)" ::: "memory");    // A(0),B(0) landed
  BAR();
  RD_AF0(LDS);
  RD_BF0(LDS + 98304);

  const int nt = K >> 6;  // 64
  int am = 0, an = 1, an2 = 2;   // A buffer rotation (t, t+1, t+2) mod 3
  for (int t = 0; t < nt; ++t) {
    const char* bA  = LDS + am * 32768;
    const char* bAn = LDS + an * 32768;
    char*       bAs = LDS + an2 * 32768;                    // A(t+2) dest
    const char* bB  = LDS + 98304 + ((t & 1) << 15);
    const char* bBn = LDS + 98304 + (((t + 1) & 1) << 15);
    char*       bBs = (char*)bB;                            // B(t+2) dest (same parity)
    const int koff2 = (t + 2) << 6;

    // ---- ph1: rd bf1(t) [4]; stage A(t+2) h0; BAR; q(0,0)
    RD_BF1(bB);
    if (t + 2 < nt) STAGE_HALF(gAbase, 0, koff2, bAs);
    BAR();
    MFMA_Q(0, 0, af0, bf0);

    // ---- ph2: rd af1(t) [8]; stage A(t+2) h1; counted vmcnt retires A(t+1);
    //      BAR; q(0,1)
    RD_AF1(bA);
    if (t + 2 < nt) STAGE_HALF(gAbase, 128, koff2, bAs + 16384);
    if (t + 1 < nt) {
      if (t + 2 < nt) {
        asm volatile("s_waitcnt vmcnt(8)" ::: "memory");  // leave {B(t+1),A(t+2)}
      } else {
        asm volatile("s_waitcnt vmcnt(4)" ::: "memory");  // tail: leave {B(t+1)}
      }
    }
    BAR();
    MFMA_Q(0, 1, af0, bf1);

    // ---- ph3: rd af0(t+1) [8] (A(t+1) landed & published at ph2 BAR);
    //      stage B(t+2) h0; BAR; q(1,0)
    if (t + 1 < nt) RD_AF0(bAn);
    if (t + 2 < nt) STAGE_HALF(gBbase, 0, koff2, bBs);
    BAR();
    MFMA_Q(1, 0, af1, bf0);

    // ---- ph4: stage B(t+2) h1; counted vmcnt retires B(t+1); BAR;
    //      rd bf0(t+1) [4]; q(1,1)
    if (t + 2 < nt) STAGE_HALF(gBbase, 128, koff2, bBs + 16384);
    if (t < nt - 2) {
      asm volatile("s_waitcnt vmcnt(8)" ::: "memory");  // leave {A(t+2),B(t+2)}
    } else if (t == nt - 2) {
      asm volatile("s_waitcnt vmcnt(0)" ::: "memory");  // tail drain
    }
    BAR();
    if (t + 1 < nt) RD_BF0(bBn);
    MFMA_Q(1, 1, af1, bf1);

    // rotate A buffers
    const int tmp = am;
    am = an; an = an2; an2 = tmp;
  }

  // ---- epilogue: C = acc + bias ----
  // C/D layout (16x16): col = lane&15, row = (lane>>4)*4 + reg  [m89/m91]
  const int row0 = bm * 256 + wm * 128;
  const int col0 = bn * 256 + wn * 64;
  float bv[4];
#pragma unroll
  for (int nf = 0; nf < 4; ++nf) bv[nf] = bias[col0 + nf * 16 + fr];

#pragma unroll
  for (int mf = 0; mf < 8; ++mf) {
#pragma unroll
    for (int nf = 0; nf < 4; ++nf) {
#pragma unroll
      for (int i = 0; i < 4; ++i) {
        const int r = row0 + mf * 16 + fq * 4 + i;
        const int c = col0 + nf * 16 + fr;
        C[(size_t)r * N + c] = acc[mf][nf][i] + bv[nf];
      }
    }
  }
}

// ---------- launcher ----------
extern "C" void kernel_launch(void* const* d_in, const int* in_sizes, int n_in,
                              void* d_out, int out_size, void* d_ws, size_t ws_size,
                              hipStream_t stream) {
  const float* x = (const float*)d_in[0];
  const float* W = (const float*)d_in[1];
  const float* b = (const float*)d_in[2];
  float* out = (float*)d_out;

  const int N = in_sizes[2];                 // 4096 (D_OUT)
  const int K = in_sizes[1] / N;             // 4096 (D_IN)
  const int M = in_sizes[0] / K;             // 8192 (B*S)

  unsigned short* Xb = (unsigned short*)d_ws;              // M*K bf16
  unsigned short* Wh = Xb + (size_t)M * K;                 // N*K bf16

  const int nblk = (int)(((size_t)N * K) / 1024);
  k_had_w<<<nblk, 256, 0, stream>>>(W, Wh);

  const long n4 = ((long)M * K) / 4;
  k_cast<<<4096, 256, 0, stream>>>(x, Xb, n4);

  const int grid = (M / 256) * (N / 256);    // 512
  k_gemm256<<<grid, 512, 0, stream>>>(Xb, Wh, b, out, M, N, K);
}

// Round 5
// 279.063 us; speedup vs baseline: 1.1407x; 1.0324x over previous
//
#include <hip/hip_runtime.h>
#include <hip/hip_bf16.h>

typedef short s16x8 __attribute__((ext_vector_type(8)));
typedef float f32x4 __attribute__((ext_vector_type(4)));

// ---------- helpers ----------
__device__ __forceinline__ unsigned short f2bf(float f) {
  unsigned u = __float_as_uint(f);
  u += 0x7fffu + ((u >> 16) & 1u);   // round-to-nearest-even
  return (unsigned short)(u >> 16);
}

__device__ __forceinline__ void gload16(const void* g, void* l) {
  __builtin_amdgcn_global_load_lds(
      (const __attribute__((address_space(1))) unsigned int*)g,
      (__attribute__((address_space(3))) unsigned int*)l,
      16, 0, 0);
}

// ---------- kernel 1: fused preprocessing ----------
// blocks [0, nblk_w): blockwise FWHT of W rows, scale 1/32, cast bf16
// blocks [nblk_w, gridDim.x): grid-stride cast x f32 -> bf16
// Both are HBM-BW-bound; fusing saves one launch gap and fills the
// hadamard tail wave with cast blocks.
__global__ void __launch_bounds__(256) k_pre(const float* __restrict__ W,
                                             unsigned short* __restrict__ Wh,
                                             const float* __restrict__ x,
                                             unsigned short* __restrict__ xb,
                                             int nblk_w, long n4) {
  __shared__ float s[1024];
  const int t = threadIdx.x;

  if (blockIdx.x < nblk_w) {
    const size_t base = (size_t)blockIdx.x * 1024;

    float4 v = reinterpret_cast<const float4*>(W + base)[t];
    s[4 * t + 0] = v.x;
    s[4 * t + 1] = v.y;
    s[4 * t + 2] = v.z;
    s[4 * t + 3] = v.w;

#pragma unroll
    for (int h = 1; h < 1024; h <<= 1) {
      __syncthreads();
#pragma unroll
      for (int pp = 0; pp < 2; ++pp) {
        int p = t + pp * 256;
        int i = ((p / h) * (h << 1)) + (p % h);
        float a = s[i], b = s[i + h];
        s[i] = a + b;
        s[i + h] = a - b;
      }
    }
    __syncthreads();

    const float sc = 0.03125f;  // 1/sqrt(1024)
    ushort4 o;
    o.x = f2bf(s[4 * t + 0] * sc);
    o.y = f2bf(s[4 * t + 1] * sc);
    o.z = f2bf(s[4 * t + 2] * sc);
    o.w = f2bf(s[4 * t + 3] * sc);
    reinterpret_cast<ushort4*>(Wh + base)[t] = o;
  } else {
    long i = (long)(blockIdx.x - nblk_w) * 256 + t;
    const long stride = (long)(gridDim.x - nblk_w) * 256;
    for (; i < n4; i += stride) {
      float4 v = reinterpret_cast<const float4*>(x)[i];
      ushort4 o;
      o.x = f2bf(v.x);
      o.y = f2bf(v.y);
      o.z = f2bf(v.z);
      o.w = f2bf(v.w);
      reinterpret_cast<ushort4*>(xb)[i] = o;
    }
  }
}

// ---------- kernel 2: 256x256 bf16 GEMM, R4 schedule + A triple-buffer ----------
// EXACT best-measured structure (237.6 us GEMM, MfmaUtil 52%, 0 conflicts).
// A: [M][K] bf16, B: [N][K] bf16, C: [M][N] f32.
// 8 waves (2M x 4N), BK=64. LDS: A 3x32KB (triple buffer) + B 2x32KB = 160KB.
// A(t+2) staged ph1/ph2, B(t+2) staged ph3/ph4, counted vmcnt(8) once per
// K-tile (leaves exactly tile-(t+2)'s 8 loads in flight), chunk-XOR swizzle
// (0-conflict measured), setprio around MFMA.
// Measured variants (do not regress to): 32x32 MFMA = 274us (4-way LDS
// conflict, swizzle-invariant); 2-barrier/phase = 266us; 4/8/8/4 reads = 244us.

#define STAGE_HALF(gbase, halfRow, koff, ldsDst)                             \
  do {                                                                       \
    gload16(gbase + (size_t)(halfRow)*K + (koff), (ldsDst) + tid * 16);      \
    gload16(gbase + (size_t)((halfRow) + 64)*K + (koff),                     \
            (ldsDst) + 8192 + tid * 16);                                     \
  } while (0)

#define RD_AF0(bufp)                                                         \
  do { _Pragma("unroll")                                                     \
    for (int i = 0; i < 4; ++i) {                                            \
      af0[i][0] = *(const s16x8*)((bufp) + aoff0 + i * 2048);                \
      af0[i][1] = *(const s16x8*)((bufp) + aoff1 + i * 2048);                \
    } } while (0)

#define RD_AF1(bufp)                                                         \
  do { _Pragma("unroll")                                                     \
    for (int i = 0; i < 4; ++i) {                                            \
      af1[i][0] = *(const s16x8*)((bufp) + aoff0 + 8192 + i * 2048);         \
      af1[i][1] = *(const s16x8*)((bufp) + aoff1 + 8192 + i * 2048);         \
    } } while (0)

#define RD_BF0(bufp)                                                         \
  do { _Pragma("unroll")                                                     \
    for (int j2 = 0; j2 < 2; ++j2) {                                         \
      bf0[j2][0] = *(const s16x8*)((bufp) + boff0 + j2 * 2048);              \
      bf0[j2][1] = *(const s16x8*)((bufp) + boff1 + j2 * 2048);              \
    } } while (0)

#define RD_BF1(bufp)                                                         \
  do { _Pragma("unroll")                                                     \
    for (int j2 = 0; j2 < 2; ++j2) {                                         \
      bf1[j2][0] = *(const s16x8*)((bufp) + boff0 + 4096 + j2 * 2048);       \
      bf1[j2][1] = *(const s16x8*)((bufp) + boff1 + 4096 + j2 * 2048);       \
    } } while (0)

#define MFMA_Q(msel, nsel, AF, BF)                                           \
  do {                                                                       \
    __builtin_amdgcn_s_setprio(1);                                           \
    _Pragma("unroll")                                                        \
    for (int kk = 0; kk < 2; ++kk) {                                         \
      _Pragma("unroll")                                                      \
      for (int i = 0; i < 4; ++i) {                                          \
        _Pragma("unroll")                                                    \
        for (int j2 = 0; j2 < 2; ++j2) {                                     \
          acc[(msel)*4 + i][(nsel)*2 + j2] =                                 \
            __builtin_amdgcn_mfma_f32_16x16x32_bf16(                         \
              AF[i][kk], BF[j2][kk], acc[(msel)*4 + i][(nsel)*2 + j2],       \
              0, 0, 0);                                                      \
        }                                                                    \
      }                                                                      \
    }                                                                        \
    __builtin_amdgcn_s_setprio(0);                                           \
  } while (0)

#define BAR() __builtin_amdgcn_s_barrier()

__global__ void __launch_bounds__(512, 2) k_gemm256(
    const unsigned short* __restrict__ A, const unsigned short* __restrict__ B,
    const float* __restrict__ bias, float* __restrict__ C,
    int M, int N, int K) {
  __shared__ char LDS[163840];   // A: 3 x 32KB @ 0/32768/65536; B: 2 x 32KB @ 98304/131072

  const int tid = threadIdx.x;
  const int lane = tid & 63;
  const int wid = tid >> 6;
  const int wm = wid >> 2;     // 0..1
  const int wn = wid & 3;      // 0..3
  const int fr = lane & 15;
  const int fq = lane >> 4;

  // XCD-aware bijective swizzle (grid = 512, divisible by 8)
  const int nbn = N >> 8;
  const int cpx = gridDim.x >> 3;
  const int swz = (blockIdx.x & 7) * cpx + (blockIdx.x >> 3);
  const int bm = swz / nbn, bn = swz % nbn;

  // ---- staging addressing (linear LDS dest, pre-swizzled global source) ----
  const int r0 = tid >> 3;
  const int ck = (tid & 7) ^ (r0 & 7);
  const unsigned short* gAbase = A + (size_t)(bm * 256 + r0) * K + ck * 8;
  const unsigned short* gBbase = B + (size_t)(bn * 256 + r0) * K + ck * 8;

  // ---- fragment read offsets, local to a 32KB tile (0-conflict pattern) ----
  const int cs0 = ((fq ^ (fr & 7)) << 4);        // kk=0 chunk byte offset
  const int cs1 = (((fq + 4) ^ (fr & 7)) << 4);  // kk=1
  const int aoff0 = wm * 16384 + fr * 128 + cs0;
  const int aoff1 = wm * 16384 + fr * 128 + cs1;
  const int bbase0 = (wn >> 1) * 16384 + (wn & 1) * 8192 + fr * 128;
  const int boff0 = bbase0 + cs0;
  const int boff1 = bbase0 + cs1;

  f32x4 acc[8][4];
#pragma unroll
  for (int m = 0; m < 8; ++m)
#pragma unroll
    for (int n = 0; n < 4; ++n)
      acc[m][n] = (f32x4){0.f, 0.f, 0.f, 0.f};

  s16x8 af0[4][2], af1[4][2], bf0[2][2], bf1[2][2];

  // ---- prologue: A(0)->bufA0, B(0)->bufB0, A(1)->bufA1, B(1)->bufB1 ----
  STAGE_HALF(gAbase, 0,   0, LDS);                    // A(0) rows 0-127
  STAGE_HALF(gAbase, 128, 0, LDS + 16384);            // A(0) rows 128-255
  STAGE_HALF(gBbase, 0,   0, LDS + 98304);            // B(0) rows 0-127
  STAGE_HALF(gBbase, 128, 0, LDS + 98304 + 16384);    // B(0) rows 128-255
  STAGE_HALF(gAbase, 0,   64, LDS + 32768);           // A(1)
  STAGE_HALF(gAbase, 128, 64, LDS + 32768 + 16384);
  STAGE_HALF(gBbase, 0,   64, LDS + 131072);          // B(1)
  STAGE_HALF(gBbase, 128, 64, LDS + 131072 + 16384);
  asm volatile("s_waitcnt vmcnt(8)" ::: "memory");    // A(0),B(0) landed
  BAR();
  RD_AF0(LDS);
  RD_BF0(LDS + 98304);

  const int nt = K >> 6;  // 64
  int am = 0, an = 1, an2 = 2;   // A buffer rotation (t, t+1, t+2) mod 3
  for (int t = 0; t < nt; ++t) {
    const char* bA  = LDS + am * 32768;
    const char* bAn = LDS + an * 32768;
    char*       bAs = LDS + an2 * 32768;                    // A(t+2) dest
    const char* bB  = LDS + 98304 + ((t & 1) << 15);
    const char* bBn = LDS + 98304 + (((t + 1) & 1) << 15);
    char*       bBs = (char*)bB;                            // B(t+2) dest (same parity)
    const int koff2 = (t + 2) << 6;

    // ---- ph1: reads bf1+af1 (12); stage A(t+2) rows 0-127; BAR; q(0,0)
    RD_BF1(bB);
    RD_AF1(bA);
    if (t + 2 < nt) STAGE_HALF(gAbase, 0, koff2, bAs);
    BAR();
    MFMA_Q(0, 0, af0, bf0);

    // ---- ph2: stage A(t+2) rows 128-255; BAR; q(0,1)
    if (t + 2 < nt) STAGE_HALF(gAbase, 128, koff2, bAs + 16384);
    BAR();
    MFMA_Q(0, 1, af0, bf1);

    // ---- ph3: stage B(t+2) rows 0-127 (bf0/bf1(t) reads drained >=1 BAR ago);
    //      BAR; q(1,0)
    if (t + 2 < nt) STAGE_HALF(gBbase, 0, koff2, bBs);
    BAR();
    MFMA_Q(1, 0, af1, bf0);

    // ---- ph4: stage B(t+2) rows 128-255; counted vmcnt; BAR;
    //      next-tile af0/bf0 reads; q(1,1)
    if (t + 2 < nt) STAGE_HALF(gBbase, 128, koff2, bBs + 16384);
    if (t < nt - 2) {
      asm volatile("s_waitcnt vmcnt(8)" ::: "memory");  // A(t+1),B(t+1) landed
    } else if (t == nt - 2) {
      asm volatile("s_waitcnt vmcnt(0)" ::: "memory");  // tail drain
    }
    BAR();
    if (t + 1 < nt) {
      RD_AF0(bAn);
      RD_BF0(bBn);
    }
    MFMA_Q(1, 1, af1, bf1);

    // rotate A buffers
    const int tmp = am;
    am = an; an = an2; an2 = tmp;
  }

  // ---- epilogue: C = acc + bias ----
  // C/D layout (16x16): col = lane&15, row = (lane>>4)*4 + reg  [m89/m91]
  const int row0 = bm * 256 + wm * 128;
  const int col0 = bn * 256 + wn * 64;
  float bv[4];
#pragma unroll
  for (int nf = 0; nf < 4; ++nf) bv[nf] = bias[col0 + nf * 16 + fr];

#pragma unroll
  for (int mf = 0; mf < 8; ++mf) {
#pragma unroll
    for (int nf = 0; nf < 4; ++nf) {
#pragma unroll
      for (int i = 0; i < 4; ++i) {
        const int r = row0 + mf * 16 + fq * 4 + i;
        const int c = col0 + nf * 16 + fr;
        C[(size_t)r * N + c] = acc[mf][nf][i] + bv[nf];
      }
    }
  }
}

// ---------- launcher ----------
extern "C" void kernel_launch(void* const* d_in, const int* in_sizes, int n_in,
                              void* d_out, int out_size, void* d_ws, size_t ws_size,
                              hipStream_t stream) {
  const float* x = (const float*)d_in[0];
  const float* W = (const float*)d_in[1];
  const float* b = (const float*)d_in[2];
  float* out = (float*)d_out;

  const int N = in_sizes[2];                 // 4096 (D_OUT)
  const int K = in_sizes[1] / N;             // 4096 (D_IN)
  const int M = in_sizes[0] / K;             // 8192 (B*S)

  unsigned short* Xb = (unsigned short*)d_ws;              // M*K bf16
  unsigned short* Wh = Xb + (size_t)M * K;                 // N*K bf16

  const int nblk_w = (int)(((size_t)N * K) / 1024);        // 16384
  const long n4 = ((long)M * K) / 4;
  k_pre<<<nblk_w + 4096, 256, 0, stream>>>(W, Wh, x, Xb, nblk_w, n4);

  const int grid = (M / 256) * (N / 256);    // 512
  k_gemm256<<<grid, 512, 0, stream>>>(Xb, Wh, b, out, M, N, K);
}